// Round 14
// baseline (185.253 us; speedup 1.0000x reference)
//
#include <hip/hip_runtime.h>
#include <math.h>

#define NPOS 110592

typedef float f32x4 __attribute__((ext_vector_type(4)));
typedef short bf16x8 __attribute__((ext_vector_type(8)));
typedef unsigned u32;
typedef u32 u32x2 __attribute__((ext_vector_type(2)));
typedef u32 u32x4 __attribute__((ext_vector_type(4)));

#define MFMA __builtin_amdgcn_mfma_f32_16x16x32_bf16

__device__ __forceinline__ short f2bf(float f) {
    u32 u = __builtin_bit_cast(u32, f);
    u += 0x7fffu + ((u >> 16) & 1u);
    return (short)(u >> 16);
}
// ALU round-to-nearest-even pack (proven rounds 1-12).
__device__ __forceinline__ u32 pack2(float a, float b) {
    return (u32)(unsigned short)f2bf(a) | ((u32)(unsigned short)f2bf(b) << 16);
}

union FragU { u32 w[4]; bf16x8 v; };
// C-layout regs (k on slots g*8+{0,1,2,3}) -> K-padded fragment, slots 4..7 = 0.
__device__ __forceinline__ bf16x8 padfrag(u32 a, u32 b) {
    FragU f; f.w[0] = a; f.w[1] = b; f.w[2] = 0u; f.w[3] = 0u; return f.v;
}

// ---- prep: bf16 qkv weights, g_in folded into columns ----
__global__ __launch_bounds__(256) void la_prep(const float* __restrict__ wqkv,
                                               const float* __restrict__ g_in,
                                               short* __restrict__ wqkv_bf)
{
    int i = blockIdx.x * 256 + threadIdx.x;
    if (i < 24576) wqkv_bf[i] = f2bf(wqkv[i] * g_in[i & 63]);
}

// ---- p01: fused pass0+pass1, 128 positions/block (1728 blocks) for 2x occupancy.
//      LDS 17.9 KB -> 6+ blocks/CU. Combine is TWO-ROUND (waves 0,1 write; waves
//      2,3 add) so the overlay fits: lctx[2][2][32][33]=16896B + lz=512B <= 17408B.
//      (Round-13 bug: lctx[4][...] = 33792B overflowed the 17920B smem.) ----
__global__ __launch_bounds__(256, 6) void la_p01(
    const float* __restrict__ x, const short* __restrict__ wkv,
    short* __restrict__ xnT, float* __restrict__ partials)
{
    __shared__ __align__(16) char smem[17920];
    char* xnz = smem;                                              // 16384 B, phase A/B
    float (*lctx)[2][32][33] = (float (*)[2][32][33])smem;         // 16896 B, phase C
    float (*lz)[2][32]       = (float (*)[2][32])(smem + 16896);   //   512 B, phase C

    const int tid = threadIdx.x, lane = tid & 63, wid = tid >> 6;
    const int g = lane >> 4, m = lane & 15;
    const int blk = blockIdx.x;
    const int batch = blk / 864;
    const int pb = (blk % 864) * 128;

    // A. x read + rmsnorm, 2 threads per position (32 channels each), swizzled stage
    {
        const int p = tid >> 1, chb = (tid & 1) * 32;
        const float* base = x + ((size_t)batch * 64 + chb) * NPOS + pb + p;
        float xv[32]; float ss = 0.f;
#pragma unroll
        for (int c = 0; c < 32; ++c) { float t = base[(size_t)c * NPOS]; xv[c] = t; ss += t * t; }
        ss += __shfl_xor(ss, 1);
        float rn = 8.0f / fmaxf(sqrtf(ss), 1e-12f);
#pragma unroll
        for (int q = 0; q < 4; ++q) {
            u32x4 w;
            w.x = pack2(xv[q*8+0] * rn, xv[q*8+1] * rn);
            w.y = pack2(xv[q*8+2] * rn, xv[q*8+3] * rn);
            w.z = pack2(xv[q*8+4] * rn, xv[q*8+5] * rn);
            w.w = pack2(xv[q*8+6] * rn, xv[q*8+7] * rn);
            int ch = (tid & 1) * 4 + q;
            *(u32x4*)(xnz + p * 128 + ((ch ^ (p & 7)) << 4)) = w;
        }
    }
    __syncthreads();

    // B. compute: wave wid -> 64 positions (cg = wid>>1), head pair hbase = (wid&1)*2.
    const int cg = wid >> 1, hbase = (wid & 1) * 2;

    bf16x8 wkA[2][2][2], wvA[2][2][2];   // [hh][tile][half], hoisted (r9-proven)
#pragma unroll
    for (int hh = 0; hh < 2; ++hh) {
#pragma unroll
        for (int dt = 0; dt < 2; ++dt) {
            const short* wr = wkv + (size_t)(128 + (hbase + hh) * 32 + dt * 16 + m) * 64 + g * 8;
            wkA[hh][dt][0] = *(const bf16x8*)wr;
            wkA[hh][dt][1] = *(const bf16x8*)(wr + 32);
        }
#pragma unroll
        for (int et = 0; et < 2; ++et) {
            const short* wr = wkv + (size_t)(256 + (hbase + hh) * 32 + et * 16 + m) * 64 + g * 8;
            wvA[hh][et][0] = *(const bf16x8*)wr;
            wvA[hh][et][1] = *(const bf16x8*)(wr + 32);
        }
    }

    f32x4 acc[2][2][2];   // [hh][dt][et] - all static indices
#pragma unroll
    for (int hh = 0; hh < 2; ++hh)
#pragma unroll
        for (int dt = 0; dt < 2; ++dt)
#pragma unroll
            for (int et = 0; et < 2; ++et) acc[hh][dt][et] = (f32x4){0.f, 0.f, 0.f, 0.f};
    float zacc[2][2] = {{0.f, 0.f}, {0.f, 0.f}};

#pragma unroll 1
    for (int ic = 0; ic < 2; ++ic) {
        bf16x8 af[2][2];
#pragma unroll
        for (int mt = 0; mt < 2; ++mt)
#pragma unroll
            for (int kf = 0; kf < 2; ++kf) {
                int rowi = cg * 64 + ic * 32 + mt * 16 + m;
                af[mt][kf] = *(const bf16x8*)(xnz + rowi * 128 + (((kf*4+g) ^ (rowi & 7)) << 4));
            }
#pragma unroll
        for (int hh = 0; hh < 2; ++hh) {
            u32 ek[2][2][2], vv[2][2][2];
#pragma unroll
            for (int dt = 0; dt < 2; ++dt) {
#pragma unroll
                for (int mt = 0; mt < 2; ++mt) {
                    f32x4 a = {0.f, 0.f, 0.f, 0.f};
                    a = MFMA(af[mt][0], wkA[hh][dt][0], a, 0, 0, 0);
                    a = MFMA(af[mt][1], wkA[hh][dt][1], a, 0, 0, 0);
                    float e0 = __expf(a[0]), e1 = __expf(a[1]);
                    float e2 = __expf(a[2]), e3 = __expf(a[3]);
                    zacc[hh][dt] += (e0 + e1) + (e2 + e3);
                    ek[dt][mt][0] = pack2(e0, e1);
                    ek[dt][mt][1] = pack2(e2, e3);
                }
            }
#pragma unroll
            for (int et = 0; et < 2; ++et) {
#pragma unroll
                for (int mt = 0; mt < 2; ++mt) {
                    f32x4 a = {0.f, 0.f, 0.f, 0.f};
                    a = MFMA(af[mt][0], wvA[hh][et][0], a, 0, 0, 0);
                    a = MFMA(af[mt][1], wvA[hh][et][1], a, 0, 0, 0);
                    vv[et][mt][0] = pack2(a[0], a[1]);
                    vv[et][mt][1] = pack2(a[2], a[3]);
                }
            }
#pragma unroll
            for (int dt = 0; dt < 2; ++dt)
#pragma unroll
                for (int et = 0; et < 2; ++et)
#pragma unroll
                    for (int mt = 0; mt < 2; ++mt)
                        acc[hh][dt][et] = MFMA(padfrag(ek[dt][mt][0], ek[dt][mt][1]),
                                               padfrag(vv[et][mt][0], vv[et][mt][1]),
                                               acc[hh][dt][et], 0, 0, 0);
        }
    }

    // xnT write-back (after compute; 128 pos x 128 B)
    char* dst = (char*)xnT + ((size_t)batch * NPOS + pb) * 128;
#pragma unroll
    for (int i = 0; i < 4; ++i) {
        int u = i * 256 + tid;
        int r = u >> 3, cl = u & 7;
        u32x4 w = *(const u32x4*)(xnz + r * 128 + ((cl ^ (r & 7)) << 4));
        *(u32x4*)(dst + (size_t)u * 16) = w;
    }

    // C. two-round combine. Head h contributors: waves {h>>1, (h>>1)+2}
    // (hp = wid&1 selects head pair; cg = wid>>1 selects position chunk).
    __syncthreads();                       // xnz reads done; overlay safe
    const int hp = wid & 1;
    if (wid < 2) {                         // Round A: cg=0 waves WRITE
#pragma unroll
        for (int hh = 0; hh < 2; ++hh)
#pragma unroll
            for (int dt = 0; dt < 2; ++dt) {
#pragma unroll
                for (int et = 0; et < 2; ++et)
#pragma unroll
                    for (int r4 = 0; r4 < 4; ++r4)
                        lctx[hp][hh][dt * 16 + g * 4 + r4][et * 16 + m] = acc[hh][dt][et][r4];
                float z = zacc[hh][dt];
                z += __shfl_xor(z, 16);
                z += __shfl_xor(z, 32);
                if (g == 0) lz[hp][hh][dt * 16 + m] = z;
            }
    }
    __syncthreads();
    if (wid >= 2) {                        // Round B: cg=1 waves ADD
#pragma unroll
        for (int hh = 0; hh < 2; ++hh)
#pragma unroll
            for (int dt = 0; dt < 2; ++dt) {
#pragma unroll
                for (int et = 0; et < 2; ++et)
#pragma unroll
                    for (int r4 = 0; r4 < 4; ++r4)
                        lctx[hp][hh][dt * 16 + g * 4 + r4][et * 16 + m] += acc[hh][dt][et][r4];
                float z = zacc[hh][dt];
                z += __shfl_xor(z, 16);
                z += __shfl_xor(z, 32);
                if (g == 0) lz[hp][hh][dt * 16 + m] += z;
            }
    }
    __syncthreads();

    float* P = partials + (size_t)blk * 4224;
    for (int i = tid; i < 4096; i += 256) {
        int h = i >> 10, de = i & 1023, d = de >> 5, e = de & 31;
        P[i] = lctx[h >> 1][h & 1][d][e];
    }
    if (tid < 128) {
        int h = tid >> 5, d = tid & 31;
        P[4096 + tid] = lz[h >> 1][h & 1][d];
    }
}

// ---- ctxt stage A: reduce 864 partials/batch -> 16 groups of 54 ----
__global__ __launch_bounds__(256) void la_ctxt_a(const float* __restrict__ partials,
                                                 float* __restrict__ part2)
{
    int t = blockIdx.x * 256 + threadIdx.x;       // 2*16*4224 = 135168 exactly
    int b = t / 67584;
    int rem = t % 67584;
    int grp = rem / 4224;
    int i = rem % 4224;
    const float* P = partials + ((size_t)(b * 864 + grp * 54)) * 4224 + i;
    float s = 0.f;
#pragma unroll 6
    for (int j = 0; j < 54; ++j) s += P[(size_t)j * 4224];
    part2[((size_t)(b * 16 + grp)) * 4224 + i] = s;
}

// ---- ctxt stage B: one block per (b,h): final sum + mem_kv fold + W2 = wout.ctx^T ----
__global__ __launch_bounds__(256) void la_ctxt_b(const float* __restrict__ part2,
                                                 const float* __restrict__ mem_kv,
                                                 const float* __restrict__ wout_f,
                                                 short* __restrict__ W2bf)
{
    __shared__ float ctxN[32][33];
    const int tid = threadIdx.x;
    const int b = blockIdx.x >> 2, h = blockIdx.x & 3;
    const float* P = part2 + (size_t)b * 16 * 4224;
#pragma unroll
    for (int u = 0; u < 4; ++u) {
        int de = tid * 4 + u;
        int d = de >> 5, e = de & 31;
        float S = 0.f, Z = 0.f;
#pragma unroll 4
        for (int grp = 0; grp < 16; ++grp) {
            S += P[(size_t)grp * 4224 + h * 1024 + de];
            Z += P[(size_t)grp * 4224 + 4096 + h * 32 + d];
        }
        const float* mk = mem_kv + (h * 32 + d) * 4;
        const float* mv = mem_kv + 512 + (h * 32 + e) * 4;
#pragma unroll
        for (int mm = 0; mm < 4; ++mm) {
            float ekv = __expf(mk[mm]);
            S += ekv * mv[mm];
            Z += ekv;
        }
        ctxN[d][e] = S / Z;
    }
    __syncthreads();
    // W2[c][h*32+d] = sum_e wout[c][h*32+e] * ctx_h[d][e]
#pragma unroll
    for (int u = 0; u < 8; ++u) {
        int idx = u * 256 + tid;          // 0..2047
        int c = idx >> 5, d = idx & 31;
        const float* wr = wout_f + c * 128 + h * 32;
        float s = 0.f;
#pragma unroll
        for (int e = 0; e < 32; ++e) s += wr[e] * ctxN[d][e];
        W2bf[(size_t)(b * 64 + c) * 128 + h * 32 + d] = f2bf(s);
    }
}

// ---- pass2: r11 verbatim. EQ GEMM -> exp -> normalize -> W2 GEMM -> rmsnorm. ----
__global__ __launch_bounds__(256, 2) void la_pass2(
    const short* __restrict__ xnT, const short* __restrict__ wq,
    const short* __restrict__ W2, const float* __restrict__ b_out,
    const float* __restrict__ g_out, float* __restrict__ out)
{
    const int tid = threadIdx.x, lane = tid & 63, wid = tid >> 6;
    const int g = lane >> 4, m = lane & 15;
    const int blk = blockIdx.x;
    const int batch = blk / 432;
    const int task = (blk % 432) * 4 + wid;   // [0, 1728): 64-pos tasks per batch
    const int posbase = task * 64;

    const short* xp = xnT + ((size_t)batch * NPOS + posbase) * 64;
    bf16x8 af[4][2];
#pragma unroll
    for (int mt = 0; mt < 4; ++mt)
#pragma unroll
        for (int kf = 0; kf < 2; ++kf)
            af[mt][kf] = *(const bf16x8*)(xp + (mt * 16 + m) * 64 + kf * 32 + g * 8);

    f32x4 oacc[4][4];   // [ct][mt]
#pragma unroll
    for (int ct = 0; ct < 4; ++ct)
#pragma unroll
        for (int mt = 0; mt < 4; ++mt) oacc[ct][mt] = (f32x4){0.f, 0.f, 0.f, 0.f};

    const float scale = 0.17677669529663687f;   // 32^-0.5
    const short* w2b = W2 + (size_t)batch * 8192;

#pragma unroll 1
    for (int h = 0; h < 4; ++h) {
        f32x4 aa[2][4];     // [dt][mt], static
#pragma unroll
        for (int dt = 0; dt < 2; ++dt) {
            const short* wr = wq + (size_t)(h * 32 + dt * 16 + m) * 64 + g * 8;
            bf16x8 a0 = *(const bf16x8*)wr;
            bf16x8 a1 = *(const bf16x8*)(wr + 32);
#pragma unroll
            for (int mt = 0; mt < 4; ++mt) {
                f32x4 a = {0.f, 0.f, 0.f, 0.f};
                a = MFMA(a0, af[mt][0], a, 0, 0, 0);
                a = MFMA(a1, af[mt][1], a, 0, 0, 0);
                aa[dt][mt][0] = __expf(a[0]);
                aa[dt][mt][1] = __expf(a[1]);
                aa[dt][mt][2] = __expf(a[2]);
                aa[dt][mt][3] = __expf(a[3]);
            }
        }
        float inv[4];
#pragma unroll
        for (int mt = 0; mt < 4; ++mt) {
            float dn = (aa[0][mt][0] + aa[0][mt][1]) + (aa[0][mt][2] + aa[0][mt][3])
                     + (aa[1][mt][0] + aa[1][mt][1]) + (aa[1][mt][2] + aa[1][mt][3]);
            dn += __shfl_xor(dn, 16);
            dn += __shfl_xor(dn, 32);
            inv[mt] = scale / dn;
        }
        u32 eqn[2][4][2];   // [dt][mt][q]
#pragma unroll
        for (int dt = 0; dt < 2; ++dt)
#pragma unroll
            for (int mt = 0; mt < 4; ++mt) {
                eqn[dt][mt][0] = pack2(aa[dt][mt][0] * inv[mt], aa[dt][mt][1] * inv[mt]);
                eqn[dt][mt][1] = pack2(aa[dt][mt][2] * inv[mt], aa[dt][mt][3] * inv[mt]);
            }
#pragma unroll
        for (int ct = 0; ct < 4; ++ct)
#pragma unroll
            for (int dt = 0; dt < 2; ++dt) {
                u32x2 wv = *(const u32x2*)(w2b + (ct * 16 + m) * 128 + h * 32 + dt * 16 + g * 4);
                bf16x8 wfr = padfrag(wv.x, wv.y);
#pragma unroll
                for (int mt = 0; mt < 4; ++mt)
                    oacc[ct][mt] = MFMA(wfr, padfrag(eqn[dt][mt][0], eqn[dt][mt][1]),
                                        oacc[ct][mt], 0, 0, 0);
            }
    }

    float bo[4][4], go[4][4];
#pragma unroll
    for (int ct = 0; ct < 4; ++ct)
#pragma unroll
        for (int r = 0; r < 4; ++r) {
            int c = ct * 16 + g * 4 + r;
            bo[ct][r] = b_out[c];
            go[ct][r] = g_out[c];
        }
    float* ob = out + (size_t)batch * 64 * NPOS;
#pragma unroll
    for (int mt = 0; mt < 4; ++mt) {
        float vv[4][4]; float s2 = 0.f;
#pragma unroll
        for (int ct = 0; ct < 4; ++ct)
#pragma unroll
            for (int r = 0; r < 4; ++r) {
                float v = oacc[ct][mt][r] + bo[ct][r];
                vv[ct][r] = v;
                s2 += v * v;
            }
        s2 += __shfl_xor(s2, 16);
        s2 += __shfl_xor(s2, 32);
        float rn2 = 8.0f / fmaxf(sqrtf(s2), 1e-12f);
        int pn = posbase + mt * 16 + m;
#pragma unroll
        for (int ct = 0; ct < 4; ++ct)
#pragma unroll
            for (int r = 0; r < 4; ++r)
                ob[(size_t)(ct * 16 + g * 4 + r) * NPOS + pn] = vv[ct][r] * rn2 * go[ct][r];
    }
}

extern "C" void kernel_launch(void* const* d_in, const int* in_sizes, int n_in,
                              void* d_out, int out_size, void* d_ws, size_t ws_size,
                              hipStream_t stream) {
    const float* x      = (const float*)d_in[0];
    const float* g_in   = (const float*)d_in[1];
    const float* w_qkv  = (const float*)d_in[2];
    const float* mem_kv = (const float*)d_in[3];
    const float* w_out  = (const float*)d_in[4];
    const float* b_out  = (const float*)d_in[5];
    const float* g_out  = (const float*)d_in[6];
    float* out = (float*)d_out;

    char* ws = (char*)d_ws;
    short* xnT     = (short*)(ws);                 // 28,311,552 B
    float* part2   = (float*)(ws + 28311552);      //    540,672 B (2*16*4224 f32)
    short* wqkv_bf = (short*)(ws + 28852224);      //     49,152 B
    short* W2bf    = (short*)(ws + 28901376);      //     32,768 B (2*64*128 bf16)

    // p01 partials (1728*4224 f32 = 29.2 MB) live in d_out scratch (56.6 MB);
    // fully consumed by la_ctxt_a before la_pass2 overwrites d_out.
    float* partials = (float*)d_out;

    la_prep<<<96, 256, 0, stream>>>(w_qkv, g_in, wqkv_bf);
    la_p01<<<1728, 256, 0, stream>>>(x, wqkv_bf, xnT, partials);
    la_ctxt_a<<<528, 256, 0, stream>>>(partials, part2);
    la_ctxt_b<<<8, 256, 0, stream>>>(part2, mem_kv, w_out, W2bf);
    la_pass2<<<864, 256, 0, stream>>>(xnT, wqkv_bf, W2bf, b_out, g_out, out);
}

// Round 15
// 113.502 us; speedup vs baseline: 1.6321x; 1.6321x over previous
//
#include <hip/hip_runtime.h>
#include <math.h>

#define NPOS 110592

typedef float f32x4 __attribute__((ext_vector_type(4)));
typedef short bf16x8 __attribute__((ext_vector_type(8)));
typedef unsigned u32;
typedef u32 u32x2 __attribute__((ext_vector_type(2)));
typedef u32 u32x4 __attribute__((ext_vector_type(4)));

#define MFMA __builtin_amdgcn_mfma_f32_16x16x32_bf16

__device__ __forceinline__ short f2bf(float f) {
    u32 u = __builtin_bit_cast(u32, f);
    u += 0x7fffu + ((u >> 16) & 1u);
    return (short)(u >> 16);
}
// ALU round-to-nearest-even pack (proven rounds 1-14).
__device__ __forceinline__ u32 pack2(float a, float b) {
    return (u32)(unsigned short)f2bf(a) | ((u32)(unsigned short)f2bf(b) << 16);
}

union FragU { u32 w[4]; bf16x8 v; };
// C-layout regs (k on slots g*8+{0,1,2,3}) -> K-padded fragment, slots 4..7 = 0.
__device__ __forceinline__ bf16x8 padfrag(u32 a, u32 b) {
    FragU f; f.w[0] = a; f.w[1] = b; f.w[2] = 0u; f.w[3] = 0u; return f.v;
}

// ---- prep: bf16 qkv weights, g_in folded into columns ----
__global__ __launch_bounds__(256) void la_prep(const float* __restrict__ wqkv,
                                               const float* __restrict__ g_in,
                                               short* __restrict__ wqkv_bf)
{
    int i = blockIdx.x * 256 + threadIdx.x;
    if (i < 24576) wqkv_bf[i] = f2bf(wqkv[i] * g_in[i & 63]);
}

// ---- p01: fused pass0+pass1, 128 positions/block (1728 blocks).
//      launch_bounds(256,4): 128-VGPR cap. Weights loaded PER-USE (r8 pattern) —
//      r14's hoist + bound(,6) capped VGPR at ~85 and spilled ~280 MB of scratch
//      traffic (FETCH 163/WRITE 234 MB, 140 us). Live set now ~90 regs. ----
__global__ __launch_bounds__(256, 4) void la_p01(
    const float* __restrict__ x, const short* __restrict__ wkv,
    short* __restrict__ xnT, float* __restrict__ partials)
{
    __shared__ __align__(16) char smem[17920];
    char* xnz = smem;                                              // 16384 B, phase A/B
    float (*lctx)[2][32][33] = (float (*)[2][32][33])smem;         // 16896 B, phase C
    float (*lz)[2][32]       = (float (*)[2][32])(smem + 16896);   //   512 B, phase C

    const int tid = threadIdx.x, lane = tid & 63, wid = tid >> 6;
    const int g = lane >> 4, m = lane & 15;
    const int blk = blockIdx.x;
    const int batch = blk / 864;
    const int pb = (blk % 864) * 128;

    // A. x read + rmsnorm, 2 threads per position (32 channels each), swizzled stage
    {
        const int p = tid >> 1, chb = (tid & 1) * 32;
        const float* base = x + ((size_t)batch * 64 + chb) * NPOS + pb + p;
        float xv[32]; float ss = 0.f;
#pragma unroll
        for (int c = 0; c < 32; ++c) { float t = base[(size_t)c * NPOS]; xv[c] = t; ss += t * t; }
        ss += __shfl_xor(ss, 1);
        float rn = 8.0f / fmaxf(sqrtf(ss), 1e-12f);
#pragma unroll
        for (int q = 0; q < 4; ++q) {
            u32x4 w;
            w.x = pack2(xv[q*8+0] * rn, xv[q*8+1] * rn);
            w.y = pack2(xv[q*8+2] * rn, xv[q*8+3] * rn);
            w.z = pack2(xv[q*8+4] * rn, xv[q*8+5] * rn);
            w.w = pack2(xv[q*8+6] * rn, xv[q*8+7] * rn);
            int ch = (tid & 1) * 4 + q;
            *(u32x4*)(xnz + p * 128 + ((ch ^ (p & 7)) << 4)) = w;
        }
    }
    __syncthreads();

    // B. compute: wave wid -> 64 positions (cg = wid>>1), head pair hbase = (wid&1)*2.
    const int cg = wid >> 1, hbase = (wid & 1) * 2;

    f32x4 acc[2][2][2];   // [hh][dt][et] - all static indices
#pragma unroll
    for (int hh = 0; hh < 2; ++hh)
#pragma unroll
        for (int dt = 0; dt < 2; ++dt)
#pragma unroll
            for (int et = 0; et < 2; ++et) acc[hh][dt][et] = (f32x4){0.f, 0.f, 0.f, 0.f};
    float zacc[2][2] = {{0.f, 0.f}, {0.f, 0.f}};

#pragma unroll 1
    for (int ic = 0; ic < 2; ++ic) {
        bf16x8 af[2][2];
#pragma unroll
        for (int mt = 0; mt < 2; ++mt)
#pragma unroll
            for (int kf = 0; kf < 2; ++kf) {
                int rowi = cg * 64 + ic * 32 + mt * 16 + m;
                af[mt][kf] = *(const bf16x8*)(xnz + rowi * 128 + (((kf*4+g) ^ (rowi & 7)) << 4));
            }
#pragma unroll
        for (int hh = 0; hh < 2; ++hh) {
            const int h = hbase + hh;
            u32 ek[2][2][2], vv[2][2][2];
#pragma unroll
            for (int dt = 0; dt < 2; ++dt) {
                const short* wr = wkv + (size_t)(128 + h * 32 + dt * 16 + m) * 64 + g * 8;
                bf16x8 w0 = *(const bf16x8*)wr;
                bf16x8 w1 = *(const bf16x8*)(wr + 32);
#pragma unroll
                for (int mt = 0; mt < 2; ++mt) {
                    f32x4 a = {0.f, 0.f, 0.f, 0.f};
                    a = MFMA(af[mt][0], w0, a, 0, 0, 0);
                    a = MFMA(af[mt][1], w1, a, 0, 0, 0);
                    float e0 = __expf(a[0]), e1 = __expf(a[1]);
                    float e2 = __expf(a[2]), e3 = __expf(a[3]);
                    zacc[hh][dt] += (e0 + e1) + (e2 + e3);
                    ek[dt][mt][0] = pack2(e0, e1);
                    ek[dt][mt][1] = pack2(e2, e3);
                }
            }
#pragma unroll
            for (int et = 0; et < 2; ++et) {
                const short* wr = wkv + (size_t)(256 + h * 32 + et * 16 + m) * 64 + g * 8;
                bf16x8 w0 = *(const bf16x8*)wr;
                bf16x8 w1 = *(const bf16x8*)(wr + 32);
#pragma unroll
                for (int mt = 0; mt < 2; ++mt) {
                    f32x4 a = {0.f, 0.f, 0.f, 0.f};
                    a = MFMA(af[mt][0], w0, a, 0, 0, 0);
                    a = MFMA(af[mt][1], w1, a, 0, 0, 0);
                    vv[et][mt][0] = pack2(a[0], a[1]);
                    vv[et][mt][1] = pack2(a[2], a[3]);
                }
            }
#pragma unroll
            for (int dt = 0; dt < 2; ++dt)
#pragma unroll
                for (int et = 0; et < 2; ++et)
#pragma unroll
                    for (int mt = 0; mt < 2; ++mt)
                        acc[hh][dt][et] = MFMA(padfrag(ek[dt][mt][0], ek[dt][mt][1]),
                                               padfrag(vv[et][mt][0], vv[et][mt][1]),
                                               acc[hh][dt][et], 0, 0, 0);
        }
    }

    // xnT write-back (after compute; 128 pos x 128 B)
    char* dst = (char*)xnT + ((size_t)batch * NPOS + pb) * 128;
#pragma unroll
    for (int i = 0; i < 4; ++i) {
        int u = i * 256 + tid;
        int r = u >> 3, cl = u & 7;
        u32x4 w = *(const u32x4*)(xnz + r * 128 + ((cl ^ (r & 7)) << 4));
        *(u32x4*)(dst + (size_t)u * 16) = w;
    }

    // C. two-round combine (r14-proven). Head h <- waves {h>>1, (h>>1)+2}.
    __syncthreads();                       // xnz reads done; overlay safe
    const int hp = wid & 1;
    if (wid < 2) {                         // Round A: cg=0 waves WRITE
#pragma unroll
        for (int hh = 0; hh < 2; ++hh)
#pragma unroll
            for (int dt = 0; dt < 2; ++dt) {
#pragma unroll
                for (int et = 0; et < 2; ++et)
#pragma unroll
                    for (int r4 = 0; r4 < 4; ++r4)
                        lctx[hp][hh][dt * 16 + g * 4 + r4][et * 16 + m] = acc[hh][dt][et][r4];
                float z = zacc[hh][dt];
                z += __shfl_xor(z, 16);
                z += __shfl_xor(z, 32);
                if (g == 0) lz[hp][hh][dt * 16 + m] = z;
            }
    }
    __syncthreads();
    if (wid >= 2) {                        // Round B: cg=1 waves ADD
#pragma unroll
        for (int hh = 0; hh < 2; ++hh)
#pragma unroll
            for (int dt = 0; dt < 2; ++dt) {
#pragma unroll
                for (int et = 0; et < 2; ++et)
#pragma unroll
                    for (int r4 = 0; r4 < 4; ++r4)
                        lctx[hp][hh][dt * 16 + g * 4 + r4][et * 16 + m] += acc[hh][dt][et][r4];
                float z = zacc[hh][dt];
                z += __shfl_xor(z, 16);
                z += __shfl_xor(z, 32);
                if (g == 0) lz[hp][hh][dt * 16 + m] += z;
            }
    }
    __syncthreads();

    float* P = partials + (size_t)blk * 4224;
    for (int i = tid; i < 4096; i += 256) {
        int h = i >> 10, de = i & 1023, d = de >> 5, e = de & 31;
        P[i] = lctx[h >> 1][h & 1][d][e];
    }
    if (tid < 128) {
        int h = tid >> 5, d = tid & 31;
        P[4096 + tid] = lz[h >> 1][h & 1][d];
    }
}

// ---- ctxt stage A: reduce 864 partials/batch -> 16 groups of 54 ----
__global__ __launch_bounds__(256) void la_ctxt_a(const float* __restrict__ partials,
                                                 float* __restrict__ part2)
{
    int t = blockIdx.x * 256 + threadIdx.x;       // 2*16*4224 = 135168 exactly
    int b = t / 67584;
    int rem = t % 67584;
    int grp = rem / 4224;
    int i = rem % 4224;
    const float* P = partials + ((size_t)(b * 864 + grp * 54)) * 4224 + i;
    float s = 0.f;
#pragma unroll 6
    for (int j = 0; j < 54; ++j) s += P[(size_t)j * 4224];
    part2[((size_t)(b * 16 + grp)) * 4224 + i] = s;
}

// ---- ctxt stage B: one block per (b,h): final sum + mem_kv fold + W2 = wout.ctx^T ----
__global__ __launch_bounds__(256) void la_ctxt_b(const float* __restrict__ part2,
                                                 const float* __restrict__ mem_kv,
                                                 const float* __restrict__ wout_f,
                                                 short* __restrict__ W2bf)
{
    __shared__ float ctxN[32][33];
    const int tid = threadIdx.x;
    const int b = blockIdx.x >> 2, h = blockIdx.x & 3;
    const float* P = part2 + (size_t)b * 16 * 4224;
#pragma unroll
    for (int u = 0; u < 4; ++u) {
        int de = tid * 4 + u;
        int d = de >> 5, e = de & 31;
        float S = 0.f, Z = 0.f;
#pragma unroll 4
        for (int grp = 0; grp < 16; ++grp) {
            S += P[(size_t)grp * 4224 + h * 1024 + de];
            Z += P[(size_t)grp * 4224 + 4096 + h * 32 + d];
        }
        const float* mk = mem_kv + (h * 32 + d) * 4;
        const float* mv = mem_kv + 512 + (h * 32 + e) * 4;
#pragma unroll
        for (int mm = 0; mm < 4; ++mm) {
            float ekv = __expf(mk[mm]);
            S += ekv * mv[mm];
            Z += ekv;
        }
        ctxN[d][e] = S / Z;
    }
    __syncthreads();
    // W2[c][h*32+d] = sum_e wout[c][h*32+e] * ctx_h[d][e]
#pragma unroll
    for (int u = 0; u < 8; ++u) {
        int idx = u * 256 + tid;          // 0..2047
        int c = idx >> 5, d = idx & 31;
        const float* wr = wout_f + c * 128 + h * 32;
        float s = 0.f;
#pragma unroll
        for (int e = 0; e < 32; ++e) s += wr[e] * ctxN[d][e];
        W2bf[(size_t)(b * 64 + c) * 128 + h * 32 + d] = f2bf(s);
    }
}

// ---- pass2: r11 verbatim. EQ GEMM -> exp -> normalize -> W2 GEMM -> rmsnorm. ----
__global__ __launch_bounds__(256, 2) void la_pass2(
    const short* __restrict__ xnT, const short* __restrict__ wq,
    const short* __restrict__ W2, const float* __restrict__ b_out,
    const float* __restrict__ g_out, float* __restrict__ out)
{
    const int tid = threadIdx.x, lane = tid & 63, wid = tid >> 6;
    const int g = lane >> 4, m = lane & 15;
    const int blk = blockIdx.x;
    const int batch = blk / 432;
    const int task = (blk % 432) * 4 + wid;   // [0, 1728): 64-pos tasks per batch
    const int posbase = task * 64;

    const short* xp = xnT + ((size_t)batch * NPOS + posbase) * 64;
    bf16x8 af[4][2];
#pragma unroll
    for (int mt = 0; mt < 4; ++mt)
#pragma unroll
        for (int kf = 0; kf < 2; ++kf)
            af[mt][kf] = *(const bf16x8*)(xp + (mt * 16 + m) * 64 + kf * 32 + g * 8);

    f32x4 oacc[4][4];   // [ct][mt]
#pragma unroll
    for (int ct = 0; ct < 4; ++ct)
#pragma unroll
        for (int mt = 0; mt < 4; ++mt) oacc[ct][mt] = (f32x4){0.f, 0.f, 0.f, 0.f};

    const float scale = 0.17677669529663687f;   // 32^-0.5
    const short* w2b = W2 + (size_t)batch * 8192;

#pragma unroll 1
    for (int h = 0; h < 4; ++h) {
        f32x4 aa[2][4];     // [dt][mt], static
#pragma unroll
        for (int dt = 0; dt < 2; ++dt) {
            const short* wr = wq + (size_t)(h * 32 + dt * 16 + m) * 64 + g * 8;
            bf16x8 a0 = *(const bf16x8*)wr;
            bf16x8 a1 = *(const bf16x8*)(wr + 32);
#pragma unroll
            for (int mt = 0; mt < 4; ++mt) {
                f32x4 a = {0.f, 0.f, 0.f, 0.f};
                a = MFMA(a0, af[mt][0], a, 0, 0, 0);
                a = MFMA(a1, af[mt][1], a, 0, 0, 0);
                aa[dt][mt][0] = __expf(a[0]);
                aa[dt][mt][1] = __expf(a[1]);
                aa[dt][mt][2] = __expf(a[2]);
                aa[dt][mt][3] = __expf(a[3]);
            }
        }
        float inv[4];
#pragma unroll
        for (int mt = 0; mt < 4; ++mt) {
            float dn = (aa[0][mt][0] + aa[0][mt][1]) + (aa[0][mt][2] + aa[0][mt][3])
                     + (aa[1][mt][0] + aa[1][mt][1]) + (aa[1][mt][2] + aa[1][mt][3]);
            dn += __shfl_xor(dn, 16);
            dn += __shfl_xor(dn, 32);
            inv[mt] = scale / dn;
        }
        u32 eqn[2][4][2];   // [dt][mt][q]
#pragma unroll
        for (int dt = 0; dt < 2; ++dt)
#pragma unroll
            for (int mt = 0; mt < 4; ++mt) {
                eqn[dt][mt][0] = pack2(aa[dt][mt][0] * inv[mt], aa[dt][mt][1] * inv[mt]);
                eqn[dt][mt][1] = pack2(aa[dt][mt][2] * inv[mt], aa[dt][mt][3] * inv[mt]);
            }
#pragma unroll
        for (int ct = 0; ct < 4; ++ct)
#pragma unroll
            for (int dt = 0; dt < 2; ++dt) {
                u32x2 wv = *(const u32x2*)(w2b + (ct * 16 + m) * 128 + h * 32 + dt * 16 + g * 4);
                bf16x8 wfr = padfrag(wv.x, wv.y);
#pragma unroll
                for (int mt = 0; mt < 4; ++mt)
                    oacc[ct][mt] = MFMA(wfr, padfrag(eqn[dt][mt][0], eqn[dt][mt][1]),
                                        oacc[ct][mt], 0, 0, 0);
            }
    }

    float bo[4][4], go[4][4];
#pragma unroll
    for (int ct = 0; ct < 4; ++ct)
#pragma unroll
        for (int r = 0; r < 4; ++r) {
            int c = ct * 16 + g * 4 + r;
            bo[ct][r] = b_out[c];
            go[ct][r] = g_out[c];
        }
    float* ob = out + (size_t)batch * 64 * NPOS;
#pragma unroll
    for (int mt = 0; mt < 4; ++mt) {
        float vv[4][4]; float s2 = 0.f;
#pragma unroll
        for (int ct = 0; ct < 4; ++ct)
#pragma unroll
            for (int r = 0; r < 4; ++r) {
                float v = oacc[ct][mt][r] + bo[ct][r];
                vv[ct][r] = v;
                s2 += v * v;
            }
        s2 += __shfl_xor(s2, 16);
        s2 += __shfl_xor(s2, 32);
        float rn2 = 8.0f / fmaxf(sqrtf(s2), 1e-12f);
        int pn = posbase + mt * 16 + m;
#pragma unroll
        for (int ct = 0; ct < 4; ++ct)
#pragma unroll
            for (int r = 0; r < 4; ++r)
                ob[(size_t)(ct * 16 + g * 4 + r) * NPOS + pn] = vv[ct][r] * rn2 * go[ct][r];
    }
}

extern "C" void kernel_launch(void* const* d_in, const int* in_sizes, int n_in,
                              void* d_out, int out_size, void* d_ws, size_t ws_size,
                              hipStream_t stream) {
    const float* x      = (const float*)d_in[0];
    const float* g_in   = (const float*)d_in[1];
    const float* w_qkv  = (const float*)d_in[2];
    const float* mem_kv = (const float*)d_in[3];
    const float* w_out  = (const float*)d_in[4];
    const float* b_out  = (const float*)d_in[5];
    const float* g_out  = (const float*)d_in[6];
    float* out = (float*)d_out;

    char* ws = (char*)d_ws;
    short* xnT     = (short*)(ws);                 // 28,311,552 B
    float* part2   = (float*)(ws + 28311552);      //    540,672 B (2*16*4224 f32)
    short* wqkv_bf = (short*)(ws + 28852224);      //     49,152 B
    short* W2bf    = (short*)(ws + 28901376);      //     32,768 B (2*64*128 bf16)

    // p01 partials (1728*4224 f32 = 29.2 MB) live in d_out scratch (56.6 MB);
    // fully consumed by la_ctxt_a before la_pass2 overwrites d_out.
    float* partials = (float*)d_out;

    la_prep<<<96, 256, 0, stream>>>(w_qkv, g_in, wqkv_bf);
    la_p01<<<1728, 256, 0, stream>>>(x, wqkv_bf, xnT, partials);
    la_ctxt_a<<<528, 256, 0, stream>>>(partials, part2);
    la_ctxt_b<<<8, 256, 0, stream>>>(part2, mem_kv, w_out, W2bf);
    la_pass2<<<864, 256, 0, stream>>>(xnT, wqkv_bf, W2bf, b_out, g_out, out);
}

// Round 16
// 100.616 us; speedup vs baseline: 1.8412x; 1.1281x over previous
//
#include <hip/hip_runtime.h>
#include <math.h>

#define NPOS 110592

typedef float f32x4 __attribute__((ext_vector_type(4)));
typedef short bf16x8 __attribute__((ext_vector_type(8)));
typedef unsigned u32;
typedef u32 u32x2 __attribute__((ext_vector_type(2)));
typedef u32 u32x4 __attribute__((ext_vector_type(4)));

#define MFMA __builtin_amdgcn_mfma_f32_16x16x32_bf16

__device__ __forceinline__ short f2bf(float f) {
    u32 u = __builtin_bit_cast(u32, f);
    u += 0x7fffu + ((u >> 16) & 1u);
    return (short)(u >> 16);
}
// ALU round-to-nearest-even pack (proven rounds 1-15).
__device__ __forceinline__ u32 pack2(float a, float b) {
    return (u32)(unsigned short)f2bf(a) | ((u32)(unsigned short)f2bf(b) << 16);
}

union FragU { u32 w[4]; bf16x8 v; };
// C-layout regs (k on slots g*8+{0,1,2,3}) -> K-padded fragment, slots 4..7 = 0.
__device__ __forceinline__ bf16x8 padfrag(u32 a, u32 b) {
    FragU f; f.w[0] = a; f.w[1] = b; f.w[2] = 0u; f.w[3] = 0u; return f.v;
}

// ---- p01: fused pass0+pass1 (r11-proven structure, 864 blocks, 256 pos/block).
//      k/v weights converted f32->bf16 ON THE FLY in the per-wave hoist (removes
//      la_prep from the critical path; transient regs die before the main loop). ----
__global__ __launch_bounds__(256, 3) void la_p01(
    const float* __restrict__ x, const float* __restrict__ wqkv_f,
    const float* __restrict__ g_in,
    short* __restrict__ xnT, float* __restrict__ partials)
{
    __shared__ __align__(16) char smem[34816];
    char* xnz = smem;                                              // 32768 B, phase A/B
    float (*lctx)[2][32][33] = (float (*)[2][32][33])smem;         // 33792 B, phase C
    float (*lz)[2][32]       = (float (*)[2][32])(smem + 33792);   //  1024 B, phase C

    const int tid = threadIdx.x, lane = tid & 63, wid = tid >> 6;
    const int g = lane >> 4, m = lane & 15;
    const int blk = blockIdx.x;
    const int batch = blk / 432;
    const int pb = (blk % 432) * 256;

    // A1. coalesced x read + in-thread rmsnorm
    const float* base = x + (size_t)batch * 64 * NPOS + pb + tid;
    float xv[64]; float ss = 0.f;
#pragma unroll
    for (int c = 0; c < 64; ++c) { float t = base[(size_t)c * NPOS]; xv[c] = t; ss += t * t; }
    float rn = 8.0f / fmaxf(sqrtf(ss), 1e-12f);

    // A2. stage bf16 row, 16B chunks XOR-swizzled (g_in folded into weights, not x)
    char* row = xnz + tid * 128;
#pragma unroll
    for (int ch = 0; ch < 8; ++ch) {
        u32x4 w;
        w.x = pack2(xv[ch*8+0] * rn, xv[ch*8+1] * rn);
        w.y = pack2(xv[ch*8+2] * rn, xv[ch*8+3] * rn);
        w.z = pack2(xv[ch*8+4] * rn, xv[ch*8+5] * rn);
        w.w = pack2(xv[ch*8+6] * rn, xv[ch*8+7] * rn);
        *(u32x4*)(row + ((ch ^ (tid & 7)) << 4)) = w;
    }
    __syncthreads();

    // B. compute: wave wid -> chunk group cg (128 pos), head pair hbase.
    const int cg = wid >> 1, hbase = (wid & 1) * 2;

    // per-lane g_in slice (transient; dies after weight build)
    float gv[2][8];
#pragma unroll
    for (int kf = 0; kf < 2; ++kf)
#pragma unroll
        for (int j = 0; j < 8; ++j) gv[kf][j] = g_in[kf * 32 + g * 8 + j];

    // Hoisted k/v weight fragments, f32 -> bf16 on the fly (== f2bf(w * g_in))
    bf16x8 wkA[2][2][2], wvA[2][2][2];   // [hh][tile][half]
#pragma unroll
    for (int hh = 0; hh < 2; ++hh) {
#pragma unroll
        for (int dt = 0; dt < 2; ++dt) {
            const float* wr = wqkv_f + (size_t)(128 + (hbase + hh) * 32 + dt * 16 + m) * 64 + g * 8;
#pragma unroll
            for (int kf = 0; kf < 2; ++kf) {
                f32x4 wa = *(const f32x4*)(wr + kf * 32);
                f32x4 wb = *(const f32x4*)(wr + kf * 32 + 4);
                FragU f;
                f.w[0] = pack2(wa[0] * gv[kf][0], wa[1] * gv[kf][1]);
                f.w[1] = pack2(wa[2] * gv[kf][2], wa[3] * gv[kf][3]);
                f.w[2] = pack2(wb[0] * gv[kf][4], wb[1] * gv[kf][5]);
                f.w[3] = pack2(wb[2] * gv[kf][6], wb[3] * gv[kf][7]);
                wkA[hh][dt][kf] = f.v;
            }
        }
#pragma unroll
        for (int et = 0; et < 2; ++et) {
            const float* wr = wqkv_f + (size_t)(256 + (hbase + hh) * 32 + et * 16 + m) * 64 + g * 8;
#pragma unroll
            for (int kf = 0; kf < 2; ++kf) {
                f32x4 wa = *(const f32x4*)(wr + kf * 32);
                f32x4 wb = *(const f32x4*)(wr + kf * 32 + 4);
                FragU f;
                f.w[0] = pack2(wa[0] * gv[kf][0], wa[1] * gv[kf][1]);
                f.w[1] = pack2(wa[2] * gv[kf][2], wa[3] * gv[kf][3]);
                f.w[2] = pack2(wb[0] * gv[kf][4], wb[1] * gv[kf][5]);
                f.w[3] = pack2(wb[2] * gv[kf][6], wb[3] * gv[kf][7]);
                wvA[hh][et][kf] = f.v;
            }
        }
    }

    f32x4 acc[2][2][2];   // [hh][dt][et] - all static indices
#pragma unroll
    for (int hh = 0; hh < 2; ++hh)
#pragma unroll
        for (int dt = 0; dt < 2; ++dt)
#pragma unroll
            for (int et = 0; et < 2; ++et) acc[hh][dt][et] = (f32x4){0.f, 0.f, 0.f, 0.f};
    float zacc[2][2] = {{0.f, 0.f}, {0.f, 0.f}};

#pragma unroll 1
    for (int ic = 0; ic < 4; ++ic) {
        bf16x8 af[2][2];
#pragma unroll
        for (int mt = 0; mt < 2; ++mt)
#pragma unroll
            for (int kf = 0; kf < 2; ++kf) {
                int rowi = cg * 128 + ic * 32 + mt * 16 + m;
                af[mt][kf] = *(const bf16x8*)(xnz + rowi * 128 + (((kf*4+g) ^ (rowi & 7)) << 4));
            }
#pragma unroll
        for (int hh = 0; hh < 2; ++hh) {
            u32 ek[2][2][2], vv[2][2][2];
#pragma unroll
            for (int dt = 0; dt < 2; ++dt) {
#pragma unroll
                for (int mt = 0; mt < 2; ++mt) {
                    f32x4 a = {0.f, 0.f, 0.f, 0.f};
                    a = MFMA(af[mt][0], wkA[hh][dt][0], a, 0, 0, 0);
                    a = MFMA(af[mt][1], wkA[hh][dt][1], a, 0, 0, 0);
                    float e0 = __expf(a[0]), e1 = __expf(a[1]);
                    float e2 = __expf(a[2]), e3 = __expf(a[3]);
                    zacc[hh][dt] += (e0 + e1) + (e2 + e3);
                    ek[dt][mt][0] = pack2(e0, e1);
                    ek[dt][mt][1] = pack2(e2, e3);
                }
            }
#pragma unroll
            for (int et = 0; et < 2; ++et) {
#pragma unroll
                for (int mt = 0; mt < 2; ++mt) {
                    f32x4 a = {0.f, 0.f, 0.f, 0.f};
                    a = MFMA(af[mt][0], wvA[hh][et][0], a, 0, 0, 0);
                    a = MFMA(af[mt][1], wvA[hh][et][1], a, 0, 0, 0);
                    vv[et][mt][0] = pack2(a[0], a[1]);
                    vv[et][mt][1] = pack2(a[2], a[3]);
                }
            }
#pragma unroll
            for (int dt = 0; dt < 2; ++dt)
#pragma unroll
                for (int et = 0; et < 2; ++et)
#pragma unroll
                    for (int mt = 0; mt < 2; ++mt)
                        acc[hh][dt][et] = MFMA(padfrag(ek[dt][mt][0], ek[dt][mt][1]),
                                               padfrag(vv[et][mt][0], vv[et][mt][1]),
                                               acc[hh][dt][et], 0, 0, 0);
        }
    }

    // A3. coalesced xnT write (after compute; stores drain in other blocks' shadow)
    char* dst = (char*)xnT + ((size_t)batch * NPOS + pb) * 128;
#pragma unroll
    for (int i = 0; i < 8; ++i) {
        int u = i * 256 + tid;
        int r = u >> 3, cl = u & 7;
        u32x4 w = *(const u32x4*)(xnz + r * 128 + ((cl ^ (r & 7)) << 4));
        *(u32x4*)(dst + (size_t)u * 16) = w;
    }

    // C. combine (r11 verbatim)
    __syncthreads();
#pragma unroll
    for (int hh = 0; hh < 2; ++hh) {
#pragma unroll
        for (int dt = 0; dt < 2; ++dt) {
#pragma unroll
            for (int et = 0; et < 2; ++et)
#pragma unroll
                for (int r4 = 0; r4 < 4; ++r4)
                    lctx[wid][hh][dt * 16 + g * 4 + r4][et * 16 + m] = acc[hh][dt][et][r4];
            float z = zacc[hh][dt];
            z += __shfl_xor(z, 16);
            z += __shfl_xor(z, 32);
            if (g == 0) lz[wid][hh][dt * 16 + m] = z;
        }
    }
    __syncthreads();

    float* P = partials + (size_t)blk * 4224;
    for (int i = tid; i < 4096; i += 256) {
        int h = i >> 10, de = i & 1023, d = de >> 5, e = de & 31;
        int w0 = h >> 1, hh2 = h & 1;
        P[i] = lctx[w0][hh2][d][e] + lctx[w0 + 2][hh2][d][e];
    }
    if (tid < 128) {
        int h = tid >> 5, d = tid & 31;
        P[4096 + tid] = lz[h >> 1][h & 1][d] + lz[(h >> 1) + 2][h & 1][d];
    }
}

// ---- ctxt stage A: reduce 432 partials/batch -> 16 groups of 27 ----
__global__ __launch_bounds__(256) void la_ctxt_a(const float* __restrict__ partials,
                                                 float* __restrict__ part2)
{
    int t = blockIdx.x * 256 + threadIdx.x;       // 2*16*4224 = 135168 exactly
    int b = t / 67584;
    int rem = t % 67584;
    int grp = rem / 4224;
    int i = rem % 4224;
    const float* P = partials + ((size_t)(b * 432 + grp * 27)) * 4224 + i;
    float s = 0.f;
#pragma unroll 3
    for (int j = 0; j < 27; ++j) s += P[(size_t)j * 4224];
    part2[((size_t)(b * 16 + grp)) * 4224 + i] = s;
}

// ---- ctxt stage B: (b,h) final sum + mem_kv fold + W2 = wout.ctx^T.
//      Also converts q-weights f32->bf16 for pass2 (la_prep folded in here). ----
__global__ __launch_bounds__(256) void la_ctxt_b(const float* __restrict__ part2,
                                                 const float* __restrict__ mem_kv,
                                                 const float* __restrict__ wout_f,
                                                 const float* __restrict__ wqkv_f,
                                                 const float* __restrict__ g_in,
                                                 short* __restrict__ W2bf,
                                                 short* __restrict__ wq_bf)
{
    __shared__ float ctxN[32][33];
    const int tid = threadIdx.x;
    const int b = blockIdx.x >> 2, h = blockIdx.x & 3;

    // q-weight conversion: 8 blocks x 1024 elems = 8192 (rows 0..127 of wqkv)
#pragma unroll
    for (int k2 = 0; k2 < 4; ++k2) {
        int i = blockIdx.x * 1024 + tid * 4 + k2;
        wq_bf[i] = f2bf(wqkv_f[i] * g_in[i & 63]);
    }

    const float* P = part2 + (size_t)b * 16 * 4224;
#pragma unroll
    for (int u = 0; u < 4; ++u) {
        int de = tid * 4 + u;
        int d = de >> 5, e = de & 31;
        float S = 0.f, Z = 0.f;
#pragma unroll 4
        for (int grp = 0; grp < 16; ++grp) {
            S += P[(size_t)grp * 4224 + h * 1024 + de];
            Z += P[(size_t)grp * 4224 + 4096 + h * 32 + d];
        }
        const float* mk = mem_kv + (h * 32 + d) * 4;
        const float* mv = mem_kv + 512 + (h * 32 + e) * 4;
#pragma unroll
        for (int mm = 0; mm < 4; ++mm) {
            float ekv = __expf(mk[mm]);
            S += ekv * mv[mm];
            Z += ekv;
        }
        ctxN[d][e] = S / Z;
    }
    __syncthreads();
    // W2[c][h*32+d] = sum_e wout[c][h*32+e] * ctx_h[d][e]
#pragma unroll
    for (int u = 0; u < 8; ++u) {
        int idx = u * 256 + tid;          // 0..2047
        int c = idx >> 5, d = idx & 31;
        const float* wr = wout_f + c * 128 + h * 32;
        float s = 0.f;
#pragma unroll
        for (int e = 0; e < 32; ++e) s += wr[e] * ctxN[d][e];
        W2bf[(size_t)(b * 64 + c) * 128 + h * 32 + d] = f2bf(s);
    }
}

// ---- pass2: r11 verbatim + non-temporal out stores (out never re-read; keeps
//      xnT/W2 resident in L2/L3). ----
__global__ __launch_bounds__(256, 2) void la_pass2(
    const short* __restrict__ xnT, const short* __restrict__ wq,
    const short* __restrict__ W2, const float* __restrict__ b_out,
    const float* __restrict__ g_out, float* __restrict__ out)
{
    const int tid = threadIdx.x, lane = tid & 63, wid = tid >> 6;
    const int g = lane >> 4, m = lane & 15;
    const int blk = blockIdx.x;
    const int batch = blk / 432;
    const int task = (blk % 432) * 4 + wid;   // [0, 1728): 64-pos tasks per batch
    const int posbase = task * 64;

    const short* xp = xnT + ((size_t)batch * NPOS + posbase) * 64;
    bf16x8 af[4][2];
#pragma unroll
    for (int mt = 0; mt < 4; ++mt)
#pragma unroll
        for (int kf = 0; kf < 2; ++kf)
            af[mt][kf] = *(const bf16x8*)(xp + (mt * 16 + m) * 64 + kf * 32 + g * 8);

    f32x4 oacc[4][4];   // [ct][mt]
#pragma unroll
    for (int ct = 0; ct < 4; ++ct)
#pragma unroll
        for (int mt = 0; mt < 4; ++mt) oacc[ct][mt] = (f32x4){0.f, 0.f, 0.f, 0.f};

    const float scale = 0.17677669529663687f;   // 32^-0.5
    const short* w2b = W2 + (size_t)batch * 8192;

#pragma unroll 1
    for (int h = 0; h < 4; ++h) {
        f32x4 aa[2][4];     // [dt][mt], static
#pragma unroll
        for (int dt = 0; dt < 2; ++dt) {
            const short* wr = wq + (size_t)(h * 32 + dt * 16 + m) * 64 + g * 8;
            bf16x8 a0 = *(const bf16x8*)wr;
            bf16x8 a1 = *(const bf16x8*)(wr + 32);
#pragma unroll
            for (int mt = 0; mt < 4; ++mt) {
                f32x4 a = {0.f, 0.f, 0.f, 0.f};
                a = MFMA(a0, af[mt][0], a, 0, 0, 0);
                a = MFMA(a1, af[mt][1], a, 0, 0, 0);
                aa[dt][mt][0] = __expf(a[0]);
                aa[dt][mt][1] = __expf(a[1]);
                aa[dt][mt][2] = __expf(a[2]);
                aa[dt][mt][3] = __expf(a[3]);
            }
        }
        float inv[4];
#pragma unroll
        for (int mt = 0; mt < 4; ++mt) {
            float dn = (aa[0][mt][0] + aa[0][mt][1]) + (aa[0][mt][2] + aa[0][mt][3])
                     + (aa[1][mt][0] + aa[1][mt][1]) + (aa[1][mt][2] + aa[1][mt][3]);
            dn += __shfl_xor(dn, 16);
            dn += __shfl_xor(dn, 32);
            inv[mt] = scale / dn;
        }
        u32 eqn[2][4][2];   // [dt][mt][q]
#pragma unroll
        for (int dt = 0; dt < 2; ++dt)
#pragma unroll
            for (int mt = 0; mt < 4; ++mt) {
                eqn[dt][mt][0] = pack2(aa[dt][mt][0] * inv[mt], aa[dt][mt][1] * inv[mt]);
                eqn[dt][mt][1] = pack2(aa[dt][mt][2] * inv[mt], aa[dt][mt][3] * inv[mt]);
            }
#pragma unroll
        for (int ct = 0; ct < 4; ++ct)
#pragma unroll
            for (int dt = 0; dt < 2; ++dt) {
                u32x2 wv = *(const u32x2*)(w2b + (ct * 16 + m) * 128 + h * 32 + dt * 16 + g * 4);
                bf16x8 wfr = padfrag(wv.x, wv.y);
#pragma unroll
                for (int mt = 0; mt < 4; ++mt)
                    oacc[ct][mt] = MFMA(wfr, padfrag(eqn[dt][mt][0], eqn[dt][mt][1]),
                                        oacc[ct][mt], 0, 0, 0);
            }
    }

    float bo[4][4], go[4][4];
#pragma unroll
    for (int ct = 0; ct < 4; ++ct)
#pragma unroll
        for (int r = 0; r < 4; ++r) {
            int c = ct * 16 + g * 4 + r;
            bo[ct][r] = b_out[c];
            go[ct][r] = g_out[c];
        }
    float* ob = out + (size_t)batch * 64 * NPOS;
#pragma unroll
    for (int mt = 0; mt < 4; ++mt) {
        float vv[4][4]; float s2 = 0.f;
#pragma unroll
        for (int ct = 0; ct < 4; ++ct)
#pragma unroll
            for (int r = 0; r < 4; ++r) {
                float v = oacc[ct][mt][r] + bo[ct][r];
                vv[ct][r] = v;
                s2 += v * v;
            }
        s2 += __shfl_xor(s2, 16);
        s2 += __shfl_xor(s2, 32);
        float rn2 = 8.0f / fmaxf(sqrtf(s2), 1e-12f);
        int pn = posbase + mt * 16 + m;
#pragma unroll
        for (int ct = 0; ct < 4; ++ct)
#pragma unroll
            for (int r = 0; r < 4; ++r)
                __builtin_nontemporal_store(vv[ct][r] * rn2 * go[ct][r],
                                            &ob[(size_t)(ct * 16 + g * 4 + r) * NPOS + pn]);
    }
}

extern "C" void kernel_launch(void* const* d_in, const int* in_sizes, int n_in,
                              void* d_out, int out_size, void* d_ws, size_t ws_size,
                              hipStream_t stream) {
    const float* x      = (const float*)d_in[0];
    const float* g_in   = (const float*)d_in[1];
    const float* w_qkv  = (const float*)d_in[2];
    const float* mem_kv = (const float*)d_in[3];
    const float* w_out  = (const float*)d_in[4];
    const float* b_out  = (const float*)d_in[5];
    const float* g_out  = (const float*)d_in[6];
    float* out = (float*)d_out;

    char* ws = (char*)d_ws;
    short* xnT   = (short*)(ws);                 // 28,311,552 B
    float* part2 = (float*)(ws + 28311552);      //    540,672 B (2*16*4224 f32)
    short* wq_bf = (short*)(ws + 28852224);      //     16,384 B (8192 bf16)
    short* W2bf  = (short*)(ws + 28868608);      //     32,768 B (2*64*128 bf16)

    // p01 partials (864*4224 f32 = 14.6 MB) live in d_out scratch; fully consumed
    // by la_ctxt_a before la_pass2 overwrites d_out with the real output.
    float* partials = (float*)d_out;

    la_p01<<<864, 256, 0, stream>>>(x, w_qkv, g_in, xnT, partials);
    la_ctxt_a<<<528, 256, 0, stream>>>(partials, part2);
    la_ctxt_b<<<8, 256, 0, stream>>>(part2, mem_kv, w_out, w_qkv, g_in, W2bf, wq_bf);
    la_pass2<<<864, 256, 0, stream>>>(xnT, wq_bf, W2bf, b_out, g_out, out);
}